// Round 2
// baseline (44422.913 us; speedup 1.0000x reference)
//
#include <hip/hip_runtime.h>

#define NN 50000
#define NE 1600000
#define NGR 64
#define XD 32
#define HID 128
#define NF 128
#define NG 50
#define GD 16
#define NL 6
#define SH 64
#define EPSF 1e-5f

// ================= CSR build (once per launch; col constant across layers) ==
__global__ __launch_bounds__(256) void k_hist(const int* __restrict__ col,
                                              int* __restrict__ hist) {
  for (int e = blockIdx.x * 256 + threadIdx.x; e < NE; e += gridDim.x * 256)
    atomicAdd(&hist[col[e]], 1);
}

// single block, 1024 threads: exclusive scan of 50000 counts -> rowptr;
// hist array is rewritten in-place with the same values to serve as cursor.
__global__ __launch_bounds__(1024) void k_scan(int* __restrict__ hist,
                                               int* __restrict__ rowptr) {
  const int tid = threadIdx.x;
  const int CH = 49;  // 1024*49 = 50176 >= NN
  const int base = tid * CH;
  int s = 0;
  for (int i = 0; i < CH; ++i) {
    int idx = base + i;
    if (idx < NN) s += hist[idx];
  }
  __shared__ int part[1024];
  part[tid] = s;
  __syncthreads();
  for (int off = 1; off < 1024; off <<= 1) {
    int v = (tid >= off) ? part[tid - off] : 0;
    __syncthreads();
    part[tid] += v;
    __syncthreads();
  }
  int run = part[tid] - s;  // exclusive prefix of this chunk
  for (int i = 0; i < CH; ++i) {
    int idx = base + i;
    if (idx < NN) {
      int c = hist[idx];
      rowptr[idx] = run;
      hist[idx] = run;  // cursor
      run += c;
    }
  }
  if (tid == 0) rowptr[NN] = NE;
}

__global__ __launch_bounds__(256) void k_scatter(const int* __restrict__ col,
                                                 int* __restrict__ cursor,
                                                 int* __restrict__ perm) {
  for (int e = blockIdx.x * 256 + threadIdx.x; e < NE; e += gridDim.x * 256) {
    int pos = atomicAdd(&cursor[col[e]], 1);
    perm[pos] = e;
  }
}

// ================= node encoder pass 1 =====================================
__global__ __launch_bounds__(256) void k_enc1(const float* __restrict__ x,
    const float* __restrict__ We1, const float* __restrict__ be1,
    float* __restrict__ t, float* __restrict__ stats) {
  int c = threadIdx.x & 127;
  int half = threadIdx.x >> 7;
  float b = be1[c];
  float psum = 0.f, psq = 0.f;
  for (int n = blockIdx.x * 2 + half; n < NN; n += gridDim.x * 2) {
    const float* xr = x + (size_t)n * XD;
    float v = b;
#pragma unroll
    for (int k = 0; k < XD; ++k) v = fmaf(xr[k], We1[k * HID + c], v);
    t[(size_t)n * HID + c] = v;
    psum += v; psq += v * v;
  }
  __shared__ float s0[256], s1[256];
  s0[threadIdx.x] = psum; s1[threadIdx.x] = psq;
  __syncthreads();
  if (threadIdx.x < 128) {
    atomicAdd(&stats[threadIdx.x], s0[threadIdx.x] + s0[threadIdx.x + 128]);
    atomicAdd(&stats[128 + threadIdx.x], s1[threadIdx.x] + s1[threadIdx.x + 128]);
  }
}

__global__ __launch_bounds__(128) void k_bn_fin(const float* __restrict__ gamma,
    const float* __restrict__ beta, float* __restrict__ stats, int C, float invn) {
  int c = threadIdx.x;
  if (c < C) {
    float mean = stats[c] * invn;
    float var = stats[128 + c] * invn - mean * mean;
    float a = gamma[c] * rsqrtf(var + EPSF);
    stats[256 + c] = a;
    stats[384 + c] = beta[c] - mean * a;
  }
}

__global__ __launch_bounds__(128) void k_enc2(const float* __restrict__ t,
    const float* __restrict__ stats, const float* __restrict__ We2,
    const float* __restrict__ be2, float* __restrict__ h) {
  __shared__ float r[HID];
  int c = threadIdx.x;
  float a = stats[256 + c], b = stats[384 + c];
  float bias = be2[c];
  for (int n = blockIdx.x; n < NN; n += gridDim.x) {
    float v = fmaf(t[(size_t)n * HID + c], a, b);
    r[c] = fmaxf(v, 0.f);
    __syncthreads();
    float acc = bias;
#pragma unroll 8
    for (int k = 0; k < HID; ++k) acc = fmaf(r[k], We2[k * HID + c], acc);
    h[(size_t)n * HID + c] = acc;
    __syncthreads();
  }
}

// ================= gaussian smearing =======================================
__global__ __launch_bounds__(256) void k_smear(const float* __restrict__ eattr,
    float* __restrict__ ea) {
  int idx = blockIdx.x * 256 + threadIdx.x;
  if (idx >= NE * NG) return;
  int e = idx / NG;
  int g = idx - e * NG;
  float ax = eattr[(size_t)e * 3], ay = eattr[(size_t)e * 3 + 1], az = eattr[(size_t)e * 3 + 2];
  float d = sqrtf(ax * ax + ay * ay + az * az);
  float off = (10.0f / 49.0f) * (float)g;
  float z = d - off;
  ea[idx] = __expf(-12.005f * z * z);  // coeff = -2401/200 exactly
}

// ================= per-layer edge kernel (CSR, no atomics) =================
// Block owns 16 consecutive destination nodes; iterates their sorted incoming
// edges in tiles of 16; accumulates into LDS agg tile; one plain store/node.
__global__ __launch_bounds__(256) void k_edge2(
    const float* __restrict__ ea, const float* __restrict__ h,
    const int* __restrict__ row, const int* __restrict__ col,
    const int* __restrict__ perm, const int* __restrict__ rowptr,
    const float* __restrict__ Wf1, const float* __restrict__ bf1,
    const float* __restrict__ Wf2, const float* __restrict__ bf2,
    float* __restrict__ agg) {
  __shared__ float agg_s[16][HID];
  __shared__ float ea_s[16][NG + 2];
  __shared__ float f1_s[16][NF];
  __shared__ float msg_s[16][NF];
  __shared__ int col_s[16];
  __shared__ int row_s[16];

  const int tid = threadIdx.x;
  const int nb = blockIdx.x * 16;
  const int eS = rowptr[nb];
  const int eE = rowptr[nb + 16];

  for (int i = tid; i < 16 * HID; i += 256) ((float*)agg_s)[i] = 0.f;

  const int ce = tid & 31;
  const int eg = tid >> 5;
  const int c0 = ce * 4;
  const int e0 = eg * 2, e1 = e0 + 1;
  const float bias1a = bf1[c0], bias1b = bf1[c0 + 1], bias1c = bf1[c0 + 2], bias1d = bf1[c0 + 3];
  const float bias2a = bf2[c0], bias2b = bf2[c0 + 1], bias2c = bf2[c0 + 2], bias2d = bf2[c0 + 3];

  for (int et = eS; et < eE; et += 16) {
    const int nval = min(16, eE - et);
    // ---- cooperative load: ea rows + col/row indices
    {
      int le = tid >> 4;        // 0..15
      int g0 = tid & 15;
      if (le < nval) {
        int pe = perm[et + le];
        const float* src = ea + (size_t)pe * NG;
        for (int g = g0; g < NG; g += 16) ea_s[le][g] = src[g];
      }
      if (tid < 16) {
        if (tid < nval) {
          int pe = perm[et + tid];
          col_s[tid] = col[pe] - nb;
          row_s[tid] = row[pe];
        } else {
          col_s[tid] = 0;
          row_s[tid] = 0;
        }
      }
    }
    __syncthreads();
    // ---- gemm1: relu(ea @ Wf1 + bf1)
    float a0[4] = {bias1a, bias1b, bias1c, bias1d};
    float a1[4] = {bias1a, bias1b, bias1c, bias1d};
    for (int g = 0; g < NG; ++g) {
      float x0 = ea_s[e0][g], x1 = ea_s[e1][g];
      float4 w = *(const float4*)(Wf1 + (size_t)g * NF + c0);
      a0[0] = fmaf(x0, w.x, a0[0]); a0[1] = fmaf(x0, w.y, a0[1]);
      a0[2] = fmaf(x0, w.z, a0[2]); a0[3] = fmaf(x0, w.w, a0[3]);
      a1[0] = fmaf(x1, w.x, a1[0]); a1[1] = fmaf(x1, w.y, a1[1]);
      a1[2] = fmaf(x1, w.z, a1[2]); a1[3] = fmaf(x1, w.w, a1[3]);
    }
    f1_s[e0][c0] = fmaxf(a0[0], 0.f); f1_s[e0][c0 + 1] = fmaxf(a0[1], 0.f);
    f1_s[e0][c0 + 2] = fmaxf(a0[2], 0.f); f1_s[e0][c0 + 3] = fmaxf(a0[3], 0.f);
    f1_s[e1][c0] = fmaxf(a1[0], 0.f); f1_s[e1][c0 + 1] = fmaxf(a1[1], 0.f);
    f1_s[e1][c0 + 2] = fmaxf(a1[2], 0.f); f1_s[e1][c0 + 3] = fmaxf(a1[3], 0.f);
    __syncthreads();
    // ---- gather h rows (hide latency before gemm2)
    int r0 = row_s[e0], r1 = row_s[e1];
    float4 h0 = *(const float4*)(h + (size_t)r0 * HID + c0);
    float4 h1 = *(const float4*)(h + (size_t)r1 * HID + c0);
    // ---- gemm2: f1 @ Wf2 + bf2
    a0[0] = bias2a; a0[1] = bias2b; a0[2] = bias2c; a0[3] = bias2d;
    a1[0] = bias2a; a1[1] = bias2b; a1[2] = bias2c; a1[3] = bias2d;
    for (int k = 0; k < NF; ++k) {
      float x0 = f1_s[e0][k], x1 = f1_s[e1][k];
      float4 w = *(const float4*)(Wf2 + (size_t)k * NF + c0);
      a0[0] = fmaf(x0, w.x, a0[0]); a0[1] = fmaf(x0, w.y, a0[1]);
      a0[2] = fmaf(x0, w.z, a0[2]); a0[3] = fmaf(x0, w.w, a0[3]);
      a1[0] = fmaf(x1, w.x, a1[0]); a1[1] = fmaf(x1, w.y, a1[1]);
      a1[2] = fmaf(x1, w.z, a1[2]); a1[3] = fmaf(x1, w.w, a1[3]);
    }
    // ---- msg = W * h[row]
    msg_s[e0][c0] = a0[0] * h0.x; msg_s[e0][c0 + 1] = a0[1] * h0.y;
    msg_s[e0][c0 + 2] = a0[2] * h0.z; msg_s[e0][c0 + 3] = a0[3] * h0.w;
    msg_s[e1][c0] = a1[0] * h1.x; msg_s[e1][c0 + 1] = a1[1] * h1.y;
    msg_s[e1][c0 + 2] = a1[2] * h1.z; msg_s[e1][c0 + 3] = a1[3] * h1.w;
    __syncthreads();
    // ---- segmented accumulate into agg_s (edges sorted by col; per-feature
    //      threads are disjoint -> no races, no atomics)
    if (tid < 128) {
      float racc = 0.f;
      int cur = col_s[0];
      for (int le = 0; le < nval; ++le) {
        int cl = col_s[le];
        if (cl != cur) { agg_s[cur][tid] += racc; racc = 0.f; cur = cl; }
        racc += msg_s[le][tid];
      }
      agg_s[cur][tid] += racc;
    }
    __syncthreads();
  }
  // ---- flush tile
  for (int i = tid; i < 16 * 32; i += 256) {
    int le = i >> 5, cj = (i & 31) * 4;
    *(float4*)(agg + (size_t)(nb + le) * HID + cj) = *(const float4*)&agg_s[le][cj];
  }
}

// ================= per-layer node update ===================================
__global__ __launch_bounds__(256) void k_node(
    const float* __restrict__ agg,
    const float* __restrict__ Wd1, const float* __restrict__ bd1,
    const float* __restrict__ Wd2, const float* __restrict__ bd2,
    float* __restrict__ h) {
  __shared__ float in_s[16][HID];
  __shared__ float r_s[16][HID];
  const int ce = threadIdx.x & 31;
  const int eg = threadIdx.x >> 5;
  const int c0 = ce * 4;
  const int n0 = eg * 2, n1 = n0 + 1;
  for (int tile = blockIdx.x; tile < NN / 16; tile += gridDim.x) {
    const int nb = tile * 16;
    for (int i = threadIdx.x; i < 16 * HID; i += 256) {
      int ln = i >> 7, k = i & 127;
      in_s[ln][k] = agg[(size_t)(nb + ln) * HID + k];
    }
    __syncthreads();
    float a0[4], a1[4];
#pragma unroll
    for (int j = 0; j < 4; ++j) { a0[j] = bd1[c0 + j]; a1[j] = a0[j]; }
    for (int k = 0; k < HID; ++k) {
      float x0 = in_s[n0][k], x1 = in_s[n1][k];
      float4 w = *(const float4*)(Wd1 + (size_t)k * HID + c0);
      a0[0] = fmaf(x0, w.x, a0[0]); a0[1] = fmaf(x0, w.y, a0[1]);
      a0[2] = fmaf(x0, w.z, a0[2]); a0[3] = fmaf(x0, w.w, a0[3]);
      a1[0] = fmaf(x1, w.x, a1[0]); a1[1] = fmaf(x1, w.y, a1[1]);
      a1[2] = fmaf(x1, w.z, a1[2]); a1[3] = fmaf(x1, w.w, a1[3]);
    }
#pragma unroll
    for (int j = 0; j < 4; ++j) {
      r_s[n0][c0 + j] = fmaxf(a0[j], 0.f);
      r_s[n1][c0 + j] = fmaxf(a1[j], 0.f);
    }
    __syncthreads();
#pragma unroll
    for (int j = 0; j < 4; ++j) { a0[j] = bd2[c0 + j]; a1[j] = a0[j]; }
    for (int k = 0; k < HID; ++k) {
      float x0 = r_s[n0][k], x1 = r_s[n1][k];
      float4 w = *(const float4*)(Wd2 + (size_t)k * HID + c0);
      a0[0] = fmaf(x0, w.x, a0[0]); a0[1] = fmaf(x0, w.y, a0[1]);
      a0[2] = fmaf(x0, w.z, a0[2]); a0[3] = fmaf(x0, w.w, a0[3]);
      a1[0] = fmaf(x1, w.x, a1[0]); a1[1] = fmaf(x1, w.y, a1[1]);
      a1[2] = fmaf(x1, w.z, a1[2]); a1[3] = fmaf(x1, w.w, a1[3]);
    }
    float4* hp0 = (float4*)(h + (size_t)(nb + n0) * HID + c0);
    float4* hp1 = (float4*)(h + (size_t)(nb + n1) * HID + c0);
    float4 v0 = *hp0, v1 = *hp1;
    v0.x += a0[0]; v0.y += a0[1]; v0.z += a0[2]; v0.w += a0[3];
    v1.x += a1[0]; v1.y += a1[1]; v1.z += a1[2]; v1.w += a1[3];
    *hp0 = v0; *hp1 = v1;
    __syncthreads();
  }
}

// ================= global MLP ==============================================
__global__ __launch_bounds__(128) void k_global(const float* __restrict__ u,
    const float* __restrict__ Wg1, const float* __restrict__ bg1,
    const float* __restrict__ gg1, const float* __restrict__ btg1,
    const float* __restrict__ Wg2, const float* __restrict__ bg2,
    float* __restrict__ u_p) {
  __shared__ float t_s[NGR][HID];
  int c = threadIdx.x;
  for (int g = 0; g < NGR; ++g) {
    float v = bg1[c];
#pragma unroll
    for (int k = 0; k < GD; ++k) v = fmaf(u[(size_t)g * GD + k], Wg1[k * HID + c], v);
    t_s[g][c] = v;
  }
  float sum = 0.f, sq = 0.f;
  for (int g = 0; g < NGR; ++g) { float v = t_s[g][c]; sum += v; sq += v * v; }
  float mean = sum * (1.f / NGR);
  float var = sq * (1.f / NGR) - mean * mean;
  float a = gg1[c] * rsqrtf(var + EPSF);
  float b = btg1[c] - mean * a;
  for (int g = 0; g < NGR; ++g) t_s[g][c] = fmaxf(fmaf(t_s[g][c], a, b), 0.f);
  __syncthreads();
  for (int g = 0; g < NGR; ++g) {
    float acc = bg2[c];
#pragma unroll 8
    for (int k = 0; k < HID; ++k) acc = fmaf(t_s[g][k], Wg2[k * HID + c], acc);
    u_p[(size_t)g * HID + c] = acc;
  }
}

// ================= shift head ==============================================
__global__ __launch_bounds__(256) void k_shift1(
    const float* __restrict__ h, const float* __restrict__ u_p,
    const int* __restrict__ batch, const float* __restrict__ Ws1,
    const float* __restrict__ bs1, float* __restrict__ t1, float* __restrict__ stats) {
  __shared__ float s_in[16][2 * HID];
  const int c = threadIdx.x & 63;
  const int ng = threadIdx.x >> 6;
  float psum = 0.f, psq = 0.f;
  for (int tile = blockIdx.x; tile < NN / 16; tile += gridDim.x) {
    const int nb = tile * 16;
    for (int i = threadIdx.x; i < 16 * HID; i += 256) {
      int ln = i >> 7, k = i & 127;
      s_in[ln][k] = h[(size_t)(nb + ln) * HID + k];
      s_in[ln][HID + k] = u_p[(size_t)batch[nb + ln] * HID + k];
    }
    __syncthreads();
    float acc[4];
#pragma unroll
    for (int j = 0; j < 4; ++j) acc[j] = bs1[c];
    for (int k = 0; k < 2 * HID; ++k) {
      float w = Ws1[k * SH + c];
#pragma unroll
      for (int j = 0; j < 4; ++j) acc[j] = fmaf(s_in[ng * 4 + j][k], w, acc[j]);
    }
#pragma unroll
    for (int j = 0; j < 4; ++j) {
      t1[(size_t)(nb + ng * 4 + j) * SH + c] = acc[j];
      psum += acc[j]; psq += acc[j] * acc[j];
    }
    __syncthreads();
  }
  __shared__ float rs[256], rq[256];
  rs[threadIdx.x] = psum; rq[threadIdx.x] = psq;
  __syncthreads();
  if (threadIdx.x < 64) {
    int c2 = threadIdx.x;
    atomicAdd(&stats[c2], rs[c2] + rs[c2 + 64] + rs[c2 + 128] + rs[c2 + 192]);
    atomicAdd(&stats[128 + c2], rq[c2] + rq[c2 + 64] + rq[c2 + 128] + rq[c2 + 192]);
  }
}

__global__ __launch_bounds__(256) void k_shift2(
    const float* __restrict__ t1, float* __restrict__ stats,
    const float* __restrict__ Ws2, const float* __restrict__ bs2,
    float* __restrict__ t2) {
  __shared__ float r_s[16][SH];
  const int c = threadIdx.x & 63;
  const int ng = threadIdx.x >> 6;
  float psum = 0.f, psq = 0.f;
  for (int tile = blockIdx.x; tile < NN / 16; tile += gridDim.x) {
    const int nb = tile * 16;
    for (int i = threadIdx.x; i < 16 * SH; i += 256) {
      int ln = i >> 6, k = i & 63;
      float v = fmaf(t1[(size_t)(nb + ln) * SH + k], stats[256 + k], stats[384 + k]);
      r_s[ln][k] = fmaxf(v, 0.f);
    }
    __syncthreads();
    float acc[4];
#pragma unroll
    for (int j = 0; j < 4; ++j) acc[j] = bs2[c];
    for (int k = 0; k < SH; ++k) {
      float w = Ws2[k * SH + c];
#pragma unroll
      for (int j = 0; j < 4; ++j) acc[j] = fmaf(r_s[ng * 4 + j][k], w, acc[j]);
    }
#pragma unroll
    for (int j = 0; j < 4; ++j) {
      t2[(size_t)(nb + ng * 4 + j) * SH + c] = acc[j];
      psum += acc[j]; psq += acc[j] * acc[j];
    }
    __syncthreads();
  }
  __shared__ float rs[256], rq[256];
  rs[threadIdx.x] = psum; rq[threadIdx.x] = psq;
  __syncthreads();
  if (threadIdx.x < 64) {
    int c2 = threadIdx.x;
    atomicAdd(&stats[c2], rs[c2] + rs[c2 + 64] + rs[c2 + 128] + rs[c2 + 192]);
    atomicAdd(&stats[128 + c2], rq[c2] + rq[c2 + 64] + rq[c2 + 128] + rq[c2 + 192]);
  }
}

__global__ __launch_bounds__(256) void k_shift3(
    const float* __restrict__ t2, const float* __restrict__ stats,
    const float* __restrict__ Ws3, const float* __restrict__ bs3,
    float* __restrict__ shifts) {
  int lane = threadIdx.x & 63;
  int n = blockIdx.x * 4 + (threadIdx.x >> 6);
  if (n >= NN) return;
  float a = stats[256 + lane], b = stats[384 + lane];
  float r = fmaxf(fmaf(t2[(size_t)n * SH + lane], a, b), 0.f);
  float v = r * Ws3[lane];
#pragma unroll
  for (int off = 32; off; off >>= 1) v += __shfl_down(v, off);
  if (lane == 0) shifts[n] = v + bs3[0];
}

extern "C" void kernel_launch(void* const* d_in, const int* in_sizes, int n_in,
                              void* d_out, int out_size, void* d_ws, size_t ws_size,
                              hipStream_t stream) {
  const float* x     = (const float*)d_in[0];
  const int*   ei    = (const int*)d_in[1];
  const float* eattr = (const float*)d_in[2];
  const int*   batch = (const int*)d_in[3];
  const float* u     = (const float*)d_in[4];
  const float* We1 = (const float*)d_in[5];  const float* be1 = (const float*)d_in[6];
  const float* ge1 = (const float*)d_in[7];  const float* bte1 = (const float*)d_in[8];
  const float* We2 = (const float*)d_in[9];  const float* be2 = (const float*)d_in[10];
  const float* Wf1 = (const float*)d_in[11]; const float* bf1 = (const float*)d_in[12];
  const float* Wf2 = (const float*)d_in[13]; const float* bf2 = (const float*)d_in[14];
  const float* Wd1 = (const float*)d_in[15]; const float* bd1 = (const float*)d_in[16];
  const float* Wd2 = (const float*)d_in[17]; const float* bd2 = (const float*)d_in[18];
  const float* Wg1 = (const float*)d_in[19]; const float* bg1 = (const float*)d_in[20];
  const float* gg1 = (const float*)d_in[21]; const float* btg1 = (const float*)d_in[22];
  const float* Wg2 = (const float*)d_in[23]; const float* bg2 = (const float*)d_in[24];
  const float* Ws1 = (const float*)d_in[25]; const float* bs1 = (const float*)d_in[26];
  const float* gs1 = (const float*)d_in[27]; const float* bts1 = (const float*)d_in[28];
  const float* Ws2 = (const float*)d_in[29]; const float* bs2 = (const float*)d_in[30];
  const float* gs2 = (const float*)d_in[31]; const float* bts2 = (const float*)d_in[32];
  const float* Ws3 = (const float*)d_in[33]; const float* bs3 = (const float*)d_in[34];

  float* out    = (float*)d_out;
  float* shifts = out;                    // [NN]
  float* h      = out + NN;               // [NN,HID]
  float* ea     = out + NN + NN * HID;    // [NE,NG]
  float* u_p    = out + NN + NN * HID + (size_t)NE * NG;  // [NGR,HID]

  // workspace layout (256B-aligned regions)
  char* wsb = (char*)d_ws;
  size_t off = 0;
  auto alloc = [&](size_t bytes) { void* p = wsb + off; off = (off + bytes + 255) & ~(size_t)255; return p; };
  float* stats  = (float*)alloc(512 * sizeof(float));
  int*   hist   = (int*)alloc((size_t)NN * sizeof(int));        // becomes cursor
  int*   rowptr = (int*)alloc((size_t)(NN + 1) * sizeof(int));
  int*   perm   = (int*)alloc((size_t)NE * sizeof(int));
  float* buf1   = (float*)alloc((size_t)NN * HID * sizeof(float));  // t / agg / t1+t2
  float* t1 = buf1;
  float* t2 = buf1 + (size_t)NN * SH;

  const int* row = ei;        // source j
  const int* col = ei + NE;   // target i

  // ---- CSR build (col constant across layers)
  hipMemsetAsync(hist, 0, (size_t)NN * sizeof(int), stream);
  k_hist<<<512, 256, 0, stream>>>(col, hist);
  k_scan<<<1, 1024, 0, stream>>>(hist, rowptr);
  k_scatter<<<512, 256, 0, stream>>>(col, hist, perm);

  // ---- node encoder
  hipMemsetAsync(stats, 0, 256 * sizeof(float), stream);
  k_enc1<<<512, 256, 0, stream>>>(x, We1, be1, buf1, stats);
  k_bn_fin<<<1, 128, 0, stream>>>(ge1, bte1, stats, 128, 1.f / NN);
  k_enc2<<<2048, 128, 0, stream>>>(buf1, stats, We2, be2, h);

  // ---- gaussian smearing
  k_smear<<<(NE * NG + 255) / 256, 256, 0, stream>>>(eattr, ea);

  // ---- interaction layers
  for (int l = 0; l < NL; ++l) {
    k_edge2<<<NN / 16, 256, 0, stream>>>(ea, h, row, col, perm, rowptr,
                                         Wf1 + (size_t)l * NG * NF, bf1 + (size_t)l * NF,
                                         Wf2 + (size_t)l * NF * NF, bf2 + (size_t)l * NF,
                                         buf1);
    k_node<<<1024, 256, 0, stream>>>(buf1,
                                     Wd1 + (size_t)l * HID * HID, bd1 + (size_t)l * HID,
                                     Wd2 + (size_t)l * HID * HID, bd2 + (size_t)l * HID,
                                     h);
  }

  // ---- global MLP
  k_global<<<1, 128, 0, stream>>>(u, Wg1, bg1, gg1, btg1, Wg2, bg2, u_p);

  // ---- shift head
  hipMemsetAsync(stats, 0, 256 * sizeof(float), stream);
  k_shift1<<<1024, 256, 0, stream>>>(h, u_p, batch, Ws1, bs1, t1, stats);
  k_bn_fin<<<1, 128, 0, stream>>>(gs1, bts1, stats, 64, 1.f / NN);
  hipMemsetAsync(stats, 0, 256 * sizeof(float), stream);
  k_shift2<<<1024, 256, 0, stream>>>(t1, stats, Ws2, bs2, t2);
  k_bn_fin<<<1, 128, 0, stream>>>(gs2, bts2, stats, 64, 1.f / NN);
  k_shift3<<<(NN + 3) / 4, 256, 0, stream>>>(t2, stats, Ws3, bs3, shifts);
}

// Round 3
// 6127.281 us; speedup vs baseline: 7.2500x; 7.2500x over previous
//
#include <hip/hip_runtime.h>

#define NN 50000
#define NE 1600000
#define NGR 64
#define XD 32
#define HID 128
#define NF 128
#define NG 50
#define GD 16
#define NL 6
#define SH 64
#define EPSF 1e-5f

typedef __bf16 bf16_t;
typedef bf16_t bf16x8 __attribute__((ext_vector_type(8)));
typedef float f32x4 __attribute__((ext_vector_type(4)));

// ================= CSR build (once; col constant across layers) ============
__global__ __launch_bounds__(256) void k_hist(const int* __restrict__ col,
                                              int* __restrict__ hist) {
  for (int e = blockIdx.x * 256 + threadIdx.x; e < NE; e += gridDim.x * 256)
    atomicAdd(&hist[col[e]], 1);
}

__global__ __launch_bounds__(1024) void k_scan(int* __restrict__ hist,
                                               int* __restrict__ rowptr) {
  const int tid = threadIdx.x;
  const int CH = 49;
  const int base = tid * CH;
  int s = 0;
  for (int i = 0; i < CH; ++i) {
    int idx = base + i;
    if (idx < NN) s += hist[idx];
  }
  __shared__ int part[1024];
  part[tid] = s;
  __syncthreads();
  for (int off = 1; off < 1024; off <<= 1) {
    int v = (tid >= off) ? part[tid - off] : 0;
    __syncthreads();
    part[tid] += v;
    __syncthreads();
  }
  int run = part[tid] - s;
  for (int i = 0; i < CH; ++i) {
    int idx = base + i;
    if (idx < NN) {
      int c = hist[idx];
      rowptr[idx] = run;
      hist[idx] = run;
      run += c;
    }
  }
  if (tid == 0) rowptr[NN] = NE;
}

__global__ __launch_bounds__(256) void k_scatter(const int* __restrict__ col,
                                                 int* __restrict__ cursor,
                                                 int* __restrict__ perm) {
  for (int e = blockIdx.x * 256 + threadIdx.x; e < NE; e += gridDim.x * 256) {
    int pos = atomicAdd(&cursor[col[e]], 1);
    perm[pos] = e;
  }
}

// ================= permuted per-edge data ==================================
__global__ __launch_bounds__(256) void k_preedge(const int* __restrict__ perm,
    const float* __restrict__ eattr, const int* __restrict__ row,
    const int* __restrict__ col, float* __restrict__ dperm,
    int* __restrict__ rowperm, int* __restrict__ destperm) {
  int p = blockIdx.x * 256 + threadIdx.x;
  if (p < NE) {
    int pe = perm[p];
    float ax = eattr[(size_t)pe * 3], ay = eattr[(size_t)pe * 3 + 1], az = eattr[(size_t)pe * 3 + 2];
    dperm[p] = sqrtf(ax * ax + ay * ay + az * az);
    rowperm[p] = row[pe];
    destperm[p] = col[pe];
  }
}

// ================= weight prep: transpose, K-pad, split hi/lo ==============
// W1T[l][c][k] (k<64, zero-padded beyond NG), W2T[l][c][k] (k<128)
__global__ __launch_bounds__(256) void k_prepw(const float* __restrict__ Wf1,
    const float* __restrict__ Wf2, bf16_t* __restrict__ W1Thi,
    bf16_t* __restrict__ W1Tlo, bf16_t* __restrict__ W2Thi,
    bf16_t* __restrict__ W2Tlo) {
  int idx = blockIdx.x * 256 + threadIdx.x;
  const int N1 = NL * 128 * 64;
  if (idx < N1) {
    int l = idx / (128 * 64);
    int r = idx - l * (128 * 64);
    int c = r >> 6, k = r & 63;
    float v = (k < NG) ? Wf1[(size_t)l * NG * NF + (size_t)k * NF + c] : 0.f;
    bf16_t hv = (bf16_t)v;
    W1Thi[idx] = hv;
    W1Tlo[idx] = (bf16_t)(v - (float)hv);
  } else {
    int j = idx - N1;
    if (j < NL * 128 * 128) {
      int l = j / (128 * 128);
      int r = j - l * (128 * 128);
      int c = r >> 7, k = r & 127;
      float v = Wf2[(size_t)l * NF * NF + (size_t)k * NF + c];
      bf16_t hv = (bf16_t)v;
      W2Thi[j] = hv;
      W2Tlo[j] = (bf16_t)(v - (float)hv);
    }
  }
}

// ================= node encoder ============================================
__global__ __launch_bounds__(256) void k_enc1(const float* __restrict__ x,
    const float* __restrict__ We1, const float* __restrict__ be1,
    float* __restrict__ t, float* __restrict__ stats) {
  int c = threadIdx.x & 127;
  int half = threadIdx.x >> 7;
  float b = be1[c];
  float psum = 0.f, psq = 0.f;
  for (int n = blockIdx.x * 2 + half; n < NN; n += gridDim.x * 2) {
    const float* xr = x + (size_t)n * XD;
    float v = b;
#pragma unroll
    for (int k = 0; k < XD; ++k) v = fmaf(xr[k], We1[k * HID + c], v);
    t[(size_t)n * HID + c] = v;
    psum += v; psq += v * v;
  }
  __shared__ float s0[256], s1[256];
  s0[threadIdx.x] = psum; s1[threadIdx.x] = psq;
  __syncthreads();
  if (threadIdx.x < 128) {
    atomicAdd(&stats[threadIdx.x], s0[threadIdx.x] + s0[threadIdx.x + 128]);
    atomicAdd(&stats[128 + threadIdx.x], s1[threadIdx.x] + s1[threadIdx.x + 128]);
  }
}

__global__ __launch_bounds__(128) void k_bn_fin(const float* __restrict__ gamma,
    const float* __restrict__ beta, float* __restrict__ stats, int C, float invn) {
  int c = threadIdx.x;
  if (c < C) {
    float mean = stats[c] * invn;
    float var = stats[128 + c] * invn - mean * mean;
    float a = gamma[c] * rsqrtf(var + EPSF);
    stats[256 + c] = a;
    stats[384 + c] = beta[c] - mean * a;
  }
}

__global__ __launch_bounds__(128) void k_enc2(const float* __restrict__ t,
    const float* __restrict__ stats, const float* __restrict__ We2,
    const float* __restrict__ be2, float* __restrict__ h) {
  __shared__ float r[HID];
  int c = threadIdx.x;
  float a = stats[256 + c], b = stats[384 + c];
  float bias = be2[c];
  for (int n = blockIdx.x; n < NN; n += gridDim.x) {
    float v = fmaf(t[(size_t)n * HID + c], a, b);
    r[c] = fmaxf(v, 0.f);
    __syncthreads();
    float acc = bias;
#pragma unroll 8
    for (int k = 0; k < HID; ++k) acc = fmaf(r[k], We2[k * HID + c], acc);
    h[(size_t)n * HID + c] = acc;
    __syncthreads();
  }
}

// ================= gaussian smearing (ea output, original order) ===========
__global__ __launch_bounds__(256) void k_smear(const float* __restrict__ eattr,
    float* __restrict__ ea) {
  int idx = blockIdx.x * 256 + threadIdx.x;
  if (idx >= NE * NG) return;
  int e = idx / NG;
  int g = idx - e * NG;
  float ax = eattr[(size_t)e * 3], ay = eattr[(size_t)e * 3 + 1], az = eattr[(size_t)e * 3 + 2];
  float d = sqrtf(ax * ax + ay * ay + az * az);
  float off = (10.0f / 49.0f) * (float)g;
  float z = d - off;
  ea[idx] = __expf(-12.005f * z * z);
}

// ================= MFMA edge kernel ========================================
// Block = 4 waves = 16 dest nodes. Per 16-edge tile:
//   A1 (ea) computed from dperm in regs (bf16 hi/lo), GEMM1 via 12 MFMA,
//   relu+split -> LDS, GEMM2 via 24 MFMA, msg = W*h[row] (f32 gather),
//   register-pre-reduced LDS atomic accumulate into agg tile.
__global__ __launch_bounds__(256) void k_edge3(
    const float* __restrict__ dperm, const int* __restrict__ rowperm,
    const int* __restrict__ destperm, const int* __restrict__ rowptr,
    const float* __restrict__ h,
    const bf16_t* __restrict__ W1Thi, const bf16_t* __restrict__ W1Tlo,
    const bf16_t* __restrict__ W2Thi, const bf16_t* __restrict__ W2Tlo,
    const float* __restrict__ bf1, const float* __restrict__ bf2,
    float* __restrict__ agg) {
  __shared__ float agg_s[16][HID];
  __shared__ bf16_t f1hi_s[16][136];
  __shared__ bf16_t f1lo_s[16][136];
  __shared__ float d_s[16];
  __shared__ int row_s[16], dst_s[16];

  const int tid = threadIdx.x;
  const int lane = tid & 63;
  const int w = tid >> 6;          // wave 0..3
  const int lm = lane & 15;        // frag row/col index
  const int lk = lane >> 4;        // k-group 0..3
  const int colbase = w * 32;      // this wave's 32 output cols
  const int nb = blockIdx.x * 16;
  const int eS = rowptr[nb], eE = rowptr[nb + 16];

  for (int i = tid; i < 16 * HID; i += 256) ((float*)agg_s)[i] = 0.f;

  // ---- B fragments in registers (once per launch) ----
  bf16x8 B1[2][2][2];  // [colfrag][kstep][hi/lo]
#pragma unroll
  for (int cf = 0; cf < 2; ++cf)
#pragma unroll
    for (int s = 0; s < 2; ++s) {
      int c = colbase + cf * 16 + lm;
      int k0 = s * 32 + lk * 8;
      B1[cf][s][0] = *(const bf16x8*)(W1Thi + (size_t)c * 64 + k0);
      B1[cf][s][1] = *(const bf16x8*)(W1Tlo + (size_t)c * 64 + k0);
    }
  bf16x8 B2[2][4][2];
#pragma unroll
  for (int cf = 0; cf < 2; ++cf)
#pragma unroll
    for (int s = 0; s < 4; ++s) {
      int c = colbase + cf * 16 + lm;
      int k0 = s * 32 + lk * 8;
      B2[cf][s][0] = *(const bf16x8*)(W2Thi + (size_t)c * 128 + k0);
      B2[cf][s][1] = *(const bf16x8*)(W2Tlo + (size_t)c * 128 + k0);
    }
  float bias1[2], bias2[2];
#pragma unroll
  for (int cf = 0; cf < 2; ++cf) {
    bias1[cf] = bf1[colbase + cf * 16 + lm];
    bias2[cf] = bf2[colbase + cf * 16 + lm];
  }

  for (int et = eS; et < eE; et += 16) {
    const int nval = min(16, eE - et);
    __syncthreads();  // meta arrays free (prev tile fully consumed)
    if (tid < 16) {
      int p = et + tid;
      if (tid < nval) {
        d_s[tid] = dperm[p];
        row_s[tid] = rowperm[p];
        dst_s[tid] = destperm[p] - nb;
      } else { d_s[tid] = 1.0e9f; row_s[tid] = 0; dst_s[tid] = 0; }
    }
    __syncthreads();

    // ---- A1 fragments: gaussians from d ----
    const float dv = d_s[lm];
    const bool ev = (lm < nval);
    bf16x8 A1hi[2], A1lo[2];
#pragma unroll
    for (int s = 0; s < 2; ++s) {
#pragma unroll
      for (int i = 0; i < 8; ++i) {
        int g = s * 32 + lk * 8 + i;
        float v = 0.f;
        if (ev && g < NG) {
          float z = dv - 0.2040816327f * (float)g;
          v = __expf(-12.005f * z * z);
        }
        bf16_t hv = (bf16_t)v;
        A1hi[s][i] = hv;
        A1lo[s][i] = (bf16_t)(v - (float)hv);
      }
    }

    // ---- GEMM1: f1 = relu(ea @ Wf1 + bf1) ----
    f32x4 acc1[2];
#pragma unroll
    for (int cf = 0; cf < 2; ++cf) {
      f32x4 a = {0.f, 0.f, 0.f, 0.f};
#pragma unroll
      for (int s = 0; s < 2; ++s) {
        a = __builtin_amdgcn_mfma_f32_16x16x32_bf16(A1hi[s], B1[cf][s][0], a, 0, 0, 0);
        a = __builtin_amdgcn_mfma_f32_16x16x32_bf16(A1hi[s], B1[cf][s][1], a, 0, 0, 0);
        a = __builtin_amdgcn_mfma_f32_16x16x32_bf16(A1lo[s], B1[cf][s][0], a, 0, 0, 0);
      }
      acc1[cf] = a;
    }
    // relu + hi/lo split -> LDS (C layout: row=lk*4+j (edge), col=lm)
#pragma unroll
    for (int cf = 0; cf < 2; ++cf) {
#pragma unroll
      for (int j = 0; j < 4; ++j) {
        int r = lk * 4 + j;
        int c = colbase + cf * 16 + lm;
        float v = fmaxf(acc1[cf][j] + bias1[cf], 0.f);
        bf16_t hv = (bf16_t)v;
        f1hi_s[r][c] = hv;
        f1lo_s[r][c] = (bf16_t)(v - (float)hv);
      }
    }
    __syncthreads();

    // ---- prefetch h rows (hide gather latency under GEMM2) ----
    float hv[2][4];
#pragma unroll
    for (int cf = 0; cf < 2; ++cf)
#pragma unroll
      for (int j = 0; j < 4; ++j) {
        int e = lk * 4 + j;
        int c = colbase + cf * 16 + lm;
        hv[cf][j] = (e < nval) ? h[(size_t)row_s[e] * HID + c] : 0.f;
      }

    // ---- GEMM2: W = f1 @ Wf2 + bf2 ----
    f32x4 acc2[2];
#pragma unroll
    for (int cf = 0; cf < 2; ++cf) acc2[cf] = (f32x4){0.f, 0.f, 0.f, 0.f};
#pragma unroll
    for (int s = 0; s < 4; ++s) {
      bf16x8 Ahi = *(const bf16x8*)&f1hi_s[lm][s * 32 + lk * 8];
      bf16x8 Alo = *(const bf16x8*)&f1lo_s[lm][s * 32 + lk * 8];
#pragma unroll
      for (int cf = 0; cf < 2; ++cf) {
        acc2[cf] = __builtin_amdgcn_mfma_f32_16x16x32_bf16(Ahi, B2[cf][s][0], acc2[cf], 0, 0, 0);
        acc2[cf] = __builtin_amdgcn_mfma_f32_16x16x32_bf16(Ahi, B2[cf][s][1], acc2[cf], 0, 0, 0);
        acc2[cf] = __builtin_amdgcn_mfma_f32_16x16x32_bf16(Alo, B2[cf][s][0], acc2[cf], 0, 0, 0);
      }
    }

    // ---- msg + register-pre-reduced LDS atomic accumulate ----
#pragma unroll
    for (int cf = 0; cf < 2; ++cf) {
      int c = colbase + cf * 16 + lm;
      float racc = 0.f;
      int cur = -1;
#pragma unroll
      for (int j = 0; j < 4; ++j) {
        int e = lk * 4 + j;
        if (e < nval) {
          int ds = dst_s[e];
          float msg = (acc2[cf][j] + bias2[cf]) * hv[cf][j];
          if (ds != cur) {
            if (cur >= 0) atomicAdd(&agg_s[cur][c], racc);
            racc = 0.f;
            cur = ds;
          }
          racc += msg;
        }
      }
      if (cur >= 0) atomicAdd(&agg_s[cur][c], racc);
    }
  }
  __syncthreads();
  // ---- flush agg tile ----
  for (int i = tid; i < 16 * 32; i += 256) {
    int le = i >> 5, cj = (i & 31) * 4;
    *(float4*)(agg + (size_t)(nb + le) * HID + cj) = *(const float4*)&agg_s[le][cj];
  }
}

// ================= per-layer node update (f32) =============================
__global__ __launch_bounds__(256) void k_node(
    const float* __restrict__ agg,
    const float* __restrict__ Wd1, const float* __restrict__ bd1,
    const float* __restrict__ Wd2, const float* __restrict__ bd2,
    float* __restrict__ h) {
  __shared__ float in_s[16][HID];
  __shared__ float r_s[16][HID];
  const int ce = threadIdx.x & 31;
  const int eg = threadIdx.x >> 5;
  const int c0 = ce * 4;
  const int n0 = eg * 2, n1 = n0 + 1;
  for (int tile = blockIdx.x; tile < NN / 16; tile += gridDim.x) {
    const int nb = tile * 16;
    for (int i = threadIdx.x; i < 16 * HID; i += 256) {
      int ln = i >> 7, k = i & 127;
      in_s[ln][k] = agg[(size_t)(nb + ln) * HID + k];
    }
    __syncthreads();
    float a0[4], a1[4];
#pragma unroll
    for (int j = 0; j < 4; ++j) { a0[j] = bd1[c0 + j]; a1[j] = a0[j]; }
    for (int k = 0; k < HID; ++k) {
      float x0 = in_s[n0][k], x1 = in_s[n1][k];
      float4 w = *(const float4*)(Wd1 + (size_t)k * HID + c0);
      a0[0] = fmaf(x0, w.x, a0[0]); a0[1] = fmaf(x0, w.y, a0[1]);
      a0[2] = fmaf(x0, w.z, a0[2]); a0[3] = fmaf(x0, w.w, a0[3]);
      a1[0] = fmaf(x1, w.x, a1[0]); a1[1] = fmaf(x1, w.y, a1[1]);
      a1[2] = fmaf(x1, w.z, a1[2]); a1[3] = fmaf(x1, w.w, a1[3]);
    }
#pragma unroll
    for (int j = 0; j < 4; ++j) {
      r_s[n0][c0 + j] = fmaxf(a0[j], 0.f);
      r_s[n1][c0 + j] = fmaxf(a1[j], 0.f);
    }
    __syncthreads();
#pragma unroll
    for (int j = 0; j < 4; ++j) { a0[j] = bd2[c0 + j]; a1[j] = a0[j]; }
    for (int k = 0; k < HID; ++k) {
      float x0 = r_s[n0][k], x1 = r_s[n1][k];
      float4 w = *(const float4*)(Wd2 + (size_t)k * HID + c0);
      a0[0] = fmaf(x0, w.x, a0[0]); a0[1] = fmaf(x0, w.y, a0[1]);
      a0[2] = fmaf(x0, w.z, a0[2]); a0[3] = fmaf(x0, w.w, a0[3]);
      a1[0] = fmaf(x1, w.x, a1[0]); a1[1] = fmaf(x1, w.y, a1[1]);
      a1[2] = fmaf(x1, w.z, a1[2]); a1[3] = fmaf(x1, w.w, a1[3]);
    }
    float4* hp0 = (float4*)(h + (size_t)(nb + n0) * HID + c0);
    float4* hp1 = (float4*)(h + (size_t)(nb + n1) * HID + c0);
    float4 v0 = *hp0, v1 = *hp1;
    v0.x += a0[0]; v0.y += a0[1]; v0.z += a0[2]; v0.w += a0[3];
    v1.x += a1[0]; v1.y += a1[1]; v1.z += a1[2]; v1.w += a1[3];
    *hp0 = v0; *hp1 = v1;
    __syncthreads();
  }
}

// ================= global MLP ==============================================
__global__ __launch_bounds__(128) void k_global(const float* __restrict__ u,
    const float* __restrict__ Wg1, const float* __restrict__ bg1,
    const float* __restrict__ gg1, const float* __restrict__ btg1,
    const float* __restrict__ Wg2, const float* __restrict__ bg2,
    float* __restrict__ u_p) {
  __shared__ float t_s[NGR][HID];
  int c = threadIdx.x;
  for (int g = 0; g < NGR; ++g) {
    float v = bg1[c];
#pragma unroll
    for (int k = 0; k < GD; ++k) v = fmaf(u[(size_t)g * GD + k], Wg1[k * HID + c], v);
    t_s[g][c] = v;
  }
  float sum = 0.f, sq = 0.f;
  for (int g = 0; g < NGR; ++g) { float v = t_s[g][c]; sum += v; sq += v * v; }
  float mean = sum * (1.f / NGR);
  float var = sq * (1.f / NGR) - mean * mean;
  float a = gg1[c] * rsqrtf(var + EPSF);
  float b = btg1[c] - mean * a;
  for (int g = 0; g < NGR; ++g) t_s[g][c] = fmaxf(fmaf(t_s[g][c], a, b), 0.f);
  __syncthreads();
  for (int g = 0; g < NGR; ++g) {
    float acc = bg2[c];
#pragma unroll 8
    for (int k = 0; k < HID; ++k) acc = fmaf(t_s[g][k], Wg2[k * HID + c], acc);
    u_p[(size_t)g * HID + c] = acc;
  }
}

// ================= shift head ==============================================
__global__ __launch_bounds__(256) void k_shift1(
    const float* __restrict__ h, const float* __restrict__ u_p,
    const int* __restrict__ batch, const float* __restrict__ Ws1,
    const float* __restrict__ bs1, float* __restrict__ t1, float* __restrict__ stats) {
  __shared__ float s_in[16][2 * HID];
  const int c = threadIdx.x & 63;
  const int ng = threadIdx.x >> 6;
  float psum = 0.f, psq = 0.f;
  for (int tile = blockIdx.x; tile < NN / 16; tile += gridDim.x) {
    const int nb = tile * 16;
    for (int i = threadIdx.x; i < 16 * HID; i += 256) {
      int ln = i >> 7, k = i & 127;
      s_in[ln][k] = h[(size_t)(nb + ln) * HID + k];
      s_in[ln][HID + k] = u_p[(size_t)batch[nb + ln] * HID + k];
    }
    __syncthreads();
    float acc[4];
#pragma unroll
    for (int j = 0; j < 4; ++j) acc[j] = bs1[c];
    for (int k = 0; k < 2 * HID; ++k) {
      float w = Ws1[k * SH + c];
#pragma unroll
      for (int j = 0; j < 4; ++j) acc[j] = fmaf(s_in[ng * 4 + j][k], w, acc[j]);
    }
#pragma unroll
    for (int j = 0; j < 4; ++j) {
      t1[(size_t)(nb + ng * 4 + j) * SH + c] = acc[j];
      psum += acc[j]; psq += acc[j] * acc[j];
    }
    __syncthreads();
  }
  __shared__ float rs[256], rq[256];
  rs[threadIdx.x] = psum; rq[threadIdx.x] = psq;
  __syncthreads();
  if (threadIdx.x < 64) {
    int c2 = threadIdx.x;
    atomicAdd(&stats[c2], rs[c2] + rs[c2 + 64] + rs[c2 + 128] + rs[c2 + 192]);
    atomicAdd(&stats[128 + c2], rq[c2] + rq[c2 + 64] + rq[c2 + 128] + rq[c2 + 192]);
  }
}

__global__ __launch_bounds__(256) void k_shift2(
    const float* __restrict__ t1, float* __restrict__ stats,
    const float* __restrict__ Ws2, const float* __restrict__ bs2,
    float* __restrict__ t2) {
  __shared__ float r_s[16][SH];
  const int c = threadIdx.x & 63;
  const int ng = threadIdx.x >> 6;
  float psum = 0.f, psq = 0.f;
  for (int tile = blockIdx.x; tile < NN / 16; tile += gridDim.x) {
    const int nb = tile * 16;
    for (int i = threadIdx.x; i < 16 * SH; i += 256) {
      int ln = i >> 6, k = i & 63;
      float v = fmaf(t1[(size_t)(nb + ln) * SH + k], stats[256 + k], stats[384 + k]);
      r_s[ln][k] = fmaxf(v, 0.f);
    }
    __syncthreads();
    float acc[4];
#pragma unroll
    for (int j = 0; j < 4; ++j) acc[j] = bs2[c];
    for (int k = 0; k < SH; ++k) {
      float w = Ws2[k * SH + c];
#pragma unroll
      for (int j = 0; j < 4; ++j) acc[j] = fmaf(r_s[ng * 4 + j][k], w, acc[j]);
    }
#pragma unroll
    for (int j = 0; j < 4; ++j) {
      t2[(size_t)(nb + ng * 4 + j) * SH + c] = acc[j];
      psum += acc[j]; psq += acc[j] * acc[j];
    }
    __syncthreads();
  }
  __shared__ float rs[256], rq[256];
  rs[threadIdx.x] = psum; rq[threadIdx.x] = psq;
  __syncthreads();
  if (threadIdx.x < 64) {
    int c2 = threadIdx.x;
    atomicAdd(&stats[c2], rs[c2] + rs[c2 + 64] + rs[c2 + 128] + rs[c2 + 192]);
    atomicAdd(&stats[128 + c2], rq[c2] + rq[c2 + 64] + rq[c2 + 128] + rq[c2 + 192]);
  }
}

__global__ __launch_bounds__(256) void k_shift3(
    const float* __restrict__ t2, const float* __restrict__ stats,
    const float* __restrict__ Ws3, const float* __restrict__ bs3,
    float* __restrict__ shifts) {
  int lane = threadIdx.x & 63;
  int n = blockIdx.x * 4 + (threadIdx.x >> 6);
  if (n >= NN) return;
  float a = stats[256 + lane], b = stats[384 + lane];
  float r = fmaxf(fmaf(t2[(size_t)n * SH + lane], a, b), 0.f);
  float v = r * Ws3[lane];
#pragma unroll
  for (int off = 32; off; off >>= 1) v += __shfl_down(v, off);
  if (lane == 0) shifts[n] = v + bs3[0];
}

extern "C" void kernel_launch(void* const* d_in, const int* in_sizes, int n_in,
                              void* d_out, int out_size, void* d_ws, size_t ws_size,
                              hipStream_t stream) {
  const float* x     = (const float*)d_in[0];
  const int*   ei    = (const int*)d_in[1];
  const float* eattr = (const float*)d_in[2];
  const int*   batch = (const int*)d_in[3];
  const float* u     = (const float*)d_in[4];
  const float* We1 = (const float*)d_in[5];  const float* be1 = (const float*)d_in[6];
  const float* ge1 = (const float*)d_in[7];  const float* bte1 = (const float*)d_in[8];
  const float* We2 = (const float*)d_in[9];  const float* be2 = (const float*)d_in[10];
  const float* Wf1 = (const float*)d_in[11]; const float* bf1 = (const float*)d_in[12];
  const float* Wf2 = (const float*)d_in[13]; const float* bf2 = (const float*)d_in[14];
  const float* Wd1 = (const float*)d_in[15]; const float* bd1 = (const float*)d_in[16];
  const float* Wd2 = (const float*)d_in[17]; const float* bd2 = (const float*)d_in[18];
  const float* Wg1 = (const float*)d_in[19]; const float* bg1 = (const float*)d_in[20];
  const float* gg1 = (const float*)d_in[21]; const float* btg1 = (const float*)d_in[22];
  const float* Wg2 = (const float*)d_in[23]; const float* bg2 = (const float*)d_in[24];
  const float* Ws1 = (const float*)d_in[25]; const float* bs1 = (const float*)d_in[26];
  const float* gs1 = (const float*)d_in[27]; const float* bts1 = (const float*)d_in[28];
  const float* Ws2 = (const float*)d_in[29]; const float* bs2 = (const float*)d_in[30];
  const float* gs2 = (const float*)d_in[31]; const float* bts2 = (const float*)d_in[32];
  const float* Ws3 = (const float*)d_in[33]; const float* bs3 = (const float*)d_in[34];

  float* out    = (float*)d_out;
  float* shifts = out;                    // [NN]
  float* h      = out + NN;               // [NN,HID]
  float* ea     = out + NN + NN * HID;    // [NE,NG]
  float* u_p    = out + NN + NN * HID + (size_t)NE * NG;  // [NGR,HID]

  // workspace layout
  char* wsb = (char*)d_ws;
  size_t off = 0;
  auto alloc = [&](size_t bytes) { void* p = wsb + off; off = (off + bytes + 255) & ~(size_t)255; return p; };
  float*  stats    = (float*)alloc(512 * sizeof(float));
  int*    hist     = (int*)alloc((size_t)NN * sizeof(int));
  int*    rowptr   = (int*)alloc((size_t)(NN + 1) * sizeof(int));
  int*    perm     = (int*)alloc((size_t)NE * sizeof(int));
  float*  dperm    = (float*)alloc((size_t)NE * sizeof(float));
  int*    rowperm  = (int*)alloc((size_t)NE * sizeof(int));
  int*    destperm = (int*)alloc((size_t)NE * sizeof(int));
  bf16_t* W1Thi    = (bf16_t*)alloc((size_t)NL * 128 * 64 * sizeof(bf16_t));
  bf16_t* W1Tlo    = (bf16_t*)alloc((size_t)NL * 128 * 64 * sizeof(bf16_t));
  bf16_t* W2Thi    = (bf16_t*)alloc((size_t)NL * 128 * 128 * sizeof(bf16_t));
  bf16_t* W2Tlo    = (bf16_t*)alloc((size_t)NL * 128 * 128 * sizeof(bf16_t));
  float*  buf1     = (float*)alloc((size_t)NN * HID * sizeof(float));
  float* t1 = buf1;
  float* t2 = buf1 + (size_t)NN * SH;

  const int* row = ei;        // source j
  const int* col = ei + NE;   // target i

  // ---- CSR build + permuted edge data + weight prep
  hipMemsetAsync(hist, 0, (size_t)NN * sizeof(int), stream);
  k_hist<<<512, 256, 0, stream>>>(col, hist);
  k_scan<<<1, 1024, 0, stream>>>(hist, rowptr);
  k_scatter<<<512, 256, 0, stream>>>(col, hist, perm);
  k_preedge<<<(NE + 255) / 256, 256, 0, stream>>>(perm, eattr, row, col,
                                                  dperm, rowperm, destperm);
  k_prepw<<<(NL * 128 * (64 + 128) + 255) / 256, 256, 0, stream>>>(
      Wf1, Wf2, W1Thi, W1Tlo, W2Thi, W2Tlo);

  // ---- node encoder
  hipMemsetAsync(stats, 0, 256 * sizeof(float), stream);
  k_enc1<<<512, 256, 0, stream>>>(x, We1, be1, buf1, stats);
  k_bn_fin<<<1, 128, 0, stream>>>(ge1, bte1, stats, 128, 1.f / NN);
  k_enc2<<<2048, 128, 0, stream>>>(buf1, stats, We2, be2, h);

  // ---- gaussian smearing (ea output)
  k_smear<<<(NE * NG + 255) / 256, 256, 0, stream>>>(eattr, ea);

  // ---- interaction layers
  for (int l = 0; l < NL; ++l) {
    k_edge3<<<NN / 16, 256, 0, stream>>>(
        dperm, rowperm, destperm, rowptr, h,
        W1Thi + (size_t)l * 128 * 64, W1Tlo + (size_t)l * 128 * 64,
        W2Thi + (size_t)l * 128 * 128, W2Tlo + (size_t)l * 128 * 128,
        bf1 + (size_t)l * NF, bf2 + (size_t)l * NF, buf1);
    k_node<<<1024, 256, 0, stream>>>(buf1,
                                     Wd1 + (size_t)l * HID * HID, bd1 + (size_t)l * HID,
                                     Wd2 + (size_t)l * HID * HID, bd2 + (size_t)l * HID,
                                     h);
  }

  // ---- global MLP
  k_global<<<1, 128, 0, stream>>>(u, Wg1, bg1, gg1, btg1, Wg2, bg2, u_p);

  // ---- shift head
  hipMemsetAsync(stats, 0, 256 * sizeof(float), stream);
  k_shift1<<<1024, 256, 0, stream>>>(h, u_p, batch, Ws1, bs1, t1, stats);
  k_bn_fin<<<1, 128, 0, stream>>>(gs1, bts1, stats, 64, 1.f / NN);
  hipMemsetAsync(stats, 0, 256 * sizeof(float), stream);
  k_shift2<<<1024, 256, 0, stream>>>(t1, stats, Ws2, bs2, t2);
  k_bn_fin<<<1, 128, 0, stream>>>(gs2, bts2, stats, 64, 1.f / NN);
  k_shift3<<<(NN + 3) / 4, 256, 0, stream>>>(t2, stats, Ws3, bs3, shifts);
}